// Round 5
// baseline (913.947 us; speedup 1.0000x reference)
//
#include <hip/hip_runtime.h>
#include <cstdint>
#include <cstddef>

#define T_LEN 16384
#define BATCH 8
#define NLAYER 9

typedef _Float16 f16;
typedef __attribute__((ext_vector_type(8))) _Float16 f16x8;
typedef __attribute__((ext_vector_type(4))) float f32x4;
#define MFMA_F16 __builtin_amdgcn_mfma_f32_16x16x32_f16

__device__ __forceinline__ float fast_sigmoid(float x) {
    return 1.0f / (1.0f + __expf(-x));
}
__device__ __forceinline__ float fast_tanh(float x) {
    return 1.0f - 2.0f / (__expf(2.0f * x) + 1.0f);
}

// ---------------------------------------------------------------------------
// Weight prepack to fp16, B-fragment order [n][k32-chunk]:
//  wA[l][ch12][n256][kp32] = conv_w[l][n][r][tap], tap = ch>>2, r = (ch&3)*32+kp
//  wB[l][ch4][n256][kp32]: n<128 -> out_w[l][n][k]; n>=128 -> output1_w[n-128][l*128+k]
// ---------------------------------------------------------------------------
__global__ __launch_bounds__(256) void prep_weights(
    const float* __restrict__ cw, const float* __restrict__ ow,
    const float* __restrict__ o1w, f16* __restrict__ wA, f16* __restrict__ wB)
{
    int n = blockIdx.x * 256 + threadIdx.x;
    const int NA = NLAYER * 12 * 256 * 32;   // 884736
    const int NB = NLAYER * 4 * 256 * 32;    // 294912
    if (n < NA) {
        int kp = n & 31; int q = n >> 5;
        int c = q & 255; q >>= 8;
        int ch = q % 12; int l = q / 12;
        int tap = ch >> 2;
        int r = (ch & 3) * 32 + kp;
        wA[n] = (f16)cw[((size_t)(l * 256 + c) * 128 + r) * 3 + tap];
    } else if (n < NA + NB) {
        int m = n - NA;
        int kp = m & 31; int q = m >> 5;
        int c = q & 255; q >>= 8;
        int ch = q & 3; int l = q >> 2;
        int k = ch * 32 + kp;
        float v = (c < 128) ? ow[(size_t)(l * 128 + c) * 128 + k]
                            : o1w[(size_t)(c - 128) * 1152 + l * 128 + k];
        wB[m] = (f16)v;
    }
}

// h[b][t][r] = tanh(iw[r]*x[b][t] + ib[r]) (fp16);  acc1 zero-init (fp16)
__global__ __launch_bounds__(256) void input_init(
    const float* __restrict__ x, const float* __restrict__ iw,
    const float* __restrict__ ib,
    f16* __restrict__ h, f16* __restrict__ acc1)
{
    int n = blockIdx.x * 256 + threadIdx.x;
    int r = n & 127; int bt = n >> 7;
    h[n] = (f16)fast_tanh(iw[r] * x[bt] + ib[r]);
    acc1[n] = (f16)0.0f;
}

// ---------------------------------------------------------------------------
// One layer. Block 256 thr = 4 waves (mg = w&1 splits M, ng = w>>1 splits N).
// Block tile M=128 x N=256; wave tile M=64 (4 m-tiles) x N=128 (8 nt,
// gate-paired: nt<4 filter j, nt>=4 gate j+128, j = ng*64+nt*16+col).
// Phase 1: B staged in LDS, XOR-swizzled (chunk i of row n stored at
//   i ^ ((n>>1)&3)) -> uniform 2-way banks on both stage-writes and
//   frag-reads. Double-buffered, 1 barrier/chunk.
// Phase 2: B direct from L2 (64 KB, 4 MFMAs/load); zs overlays the Bs
//   region (union) -> LDS total 34.8 KB.
// ---------------------------------------------------------------------------
__global__ __launch_bounds__(256, 2) void layer_kernel(
    const f16* __restrict__ h_in, f16* __restrict__ h_out,
    f16* __restrict__ acc1,
    const f16* __restrict__ wA,   // [12][256][32] this layer
    const f16* __restrict__ wB,   // [4][256][32]  this layer
    const float* __restrict__ cb, // conv_b [256]
    const float* __restrict__ ob, // out_b  [128]
    int d)
{
    __shared__ __align__(16) char smem_raw[34816];
    f16* const Bsm = (f16*)smem_raw;          // phase 1: [2][8192] (32 KB)
    f16* const zs  = (f16*)smem_raw;          // phase 2: [128][136] (34.8 KB)

    const int tid  = threadIdx.x;
    const int lane = tid & 63;
    const int w4   = tid >> 6;
    const int mg   = w4 & 1;
    const int ng   = w4 >> 1;
    const int col  = lane & 15;
    const int quad = lane >> 4;
    const int b    = blockIdx.y;
    const int t0   = blockIdx.x * 128;

    const f16* hb = h_in + (size_t)b * T_LEN * 128;

    const int bswz = (quad ^ ((col >> 1) & 3)) * 8;  // swizzled chunk offset (reads)
    const int wsw  = (tid >> 1) & 3;                 // staging-write swizzle

    f32x4 acc[4][8];
#pragma unroll
    for (int mt = 0; mt < 4; ++mt)
#pragma unroll
        for (int nt = 0; nt < 8; ++nt) acc[mt][nt] = (f32x4)0.0f;

    // ---------------- Phase 1: pre = h * WA, K=384 (12 chunks of 32) --------
    f16x8 sv[4];
    {
        const f16* src = wA + tid * 32;       // chunk 0
#pragma unroll
        for (int i = 0; i < 4; ++i) sv[i] = *(const f16x8*)&src[i * 8];
#pragma unroll
        for (int i = 0; i < 4; ++i)
            *(f16x8*)&Bsm[tid * 32 + ((i ^ wsw) * 8)] = sv[i];
    }
    __syncthreads();

#pragma unroll
    for (int ch = 0; ch < 12; ++ch) {
        if (ch < 11) {
            const f16* src = wA + (ch + 1) * 8192 + tid * 32;
#pragma unroll
            for (int i = 0; i < 4; ++i) sv[i] = *(const f16x8*)&src[i * 8];
        }
        const int tap = ch >> 2;
        const int off = (2 - tap) * d;
        const int kb  = (ch & 3) * 32 + quad * 8;
        f16x8 a[4];
#pragma unroll
        for (int mt = 0; mt < 4; ++mt) {
            int t = t0 + mg * 64 + mt * 16 + col - off;
            if (t >= 0) a[mt] = *(const f16x8*)&hb[(size_t)t * 128 + kb];
            else        a[mt] = (f16x8)(f16)0.0f;
        }
        const f16* bsc = Bsm + (ch & 1) * 8192;
#pragma unroll
        for (int nt = 0; nt < 8; ++nt) {
            int nb = (nt < 4) ? (ng * 64 + nt * 16) : (128 + ng * 64 + (nt - 4) * 16);
            f16x8 bf = *(const f16x8*)&bsc[(nb + col) * 32 + bswz];
            acc[0][nt] = MFMA_F16(a[0], bf, acc[0][nt], 0, 0, 0);
            acc[1][nt] = MFMA_F16(a[1], bf, acc[1][nt], 0, 0, 0);
            acc[2][nt] = MFMA_F16(a[2], bf, acc[2][nt], 0, 0, 0);
            acc[3][nt] = MFMA_F16(a[3], bf, acc[3][nt], 0, 0, 0);
        }
        if (ch < 11) {
            f16* dst = Bsm + ((ch + 1) & 1) * 8192 + tid * 32;
#pragma unroll
            for (int i = 0; i < 4; ++i) *(f16x8*)&dst[(i ^ wsw) * 8] = sv[i];
        }
        __syncthreads();
    }

    // ---------------- Gating -> zs[128][136] (overlays Bsm; reads drained) --
#pragma unroll
    for (int nt = 0; nt < 4; ++nt) {
        int j = ng * 64 + nt * 16 + col;
        float cf = cb[j];
        float cg = cb[j + 128];
#pragma unroll
        for (int mt = 0; mt < 4; ++mt)
#pragma unroll
            for (int reg = 0; reg < 4; ++reg) {
                float f = acc[mt][nt][reg]     + cf;
                float g = acc[mt][nt + 4][reg] + cg;
                zs[(mg * 64 + mt * 16 + quad * 4 + reg) * 136 + j] =
                    (f16)(fast_tanh(f) * fast_sigmoid(g));
            }
    }
    __syncthreads();

    // ---------------- Phase 2: [res|skip] = z * WB, K=128; B from L2 --------
#pragma unroll
    for (int mt = 0; mt < 4; ++mt)
#pragma unroll
        for (int nt = 0; nt < 8; ++nt) acc[mt][nt] = (f32x4)0.0f;

#pragma unroll
    for (int ch = 0; ch < 4; ++ch) {
        f16x8 a[4];
#pragma unroll
        for (int mt = 0; mt < 4; ++mt)
            a[mt] = *(const f16x8*)&zs[(mg * 64 + mt * 16 + col) * 136 + ch * 32 + quad * 8];
        const f16* wc = wB + ch * 8192;
#pragma unroll
        for (int nt = 0; nt < 8; ++nt) {
            int nb = (nt < 4) ? (ng * 64 + nt * 16) : (128 + ng * 64 + (nt - 4) * 16);
            f16x8 bf = *(const f16x8*)&wc[(nb + col) * 32 + quad * 8];
            acc[0][nt] = MFMA_F16(a[0], bf, acc[0][nt], 0, 0, 0);
            acc[1][nt] = MFMA_F16(a[1], bf, acc[1][nt], 0, 0, 0);
            acc[2][nt] = MFMA_F16(a[2], bf, acc[2][nt], 0, 0, 0);
            acc[3][nt] = MFMA_F16(a[3], bf, acc[3][nt], 0, 0, 0);
        }
    }
    __syncthreads();   // zs reads drained before epilogue overwrite

    // ---------------- Epilogue 1: h_out = h_in + res + ob (zs xpose) --------
#pragma unroll
    for (int nt = 0; nt < 4; ++nt) {
        int n = ng * 64 + nt * 16 + col;
        float o = ob[n];
#pragma unroll
        for (int mt = 0; mt < 4; ++mt)
#pragma unroll
            for (int reg = 0; reg < 4; ++reg)
                zs[(mg * 64 + mt * 16 + quad * 4 + reg) * 136 + n] =
                    (f16)(acc[mt][nt][reg] + o);
    }
    __syncthreads();
    const int orow = tid >> 1, oseg = tid & 1;
    const size_t gb = (size_t)b * T_LEN * 128 + (size_t)(t0 + orow) * 128 + oseg * 64;
#pragma unroll
    for (int i = 0; i < 8; ++i) {
        f16x8 rv = *(const f16x8*)&zs[orow * 136 + oseg * 64 + i * 8];
        f16x8 hv = *(const f16x8*)&h_in[gb + i * 8];
        *(f16x8*)&h_out[gb + i * 8] = hv + rv;
    }
    __syncthreads();

    // ---------------- Epilogue 2: acc1 += skip (zs xpose) -------------------
#pragma unroll
    for (int nt = 0; nt < 4; ++nt) {
        int n = ng * 64 + nt * 16 + col;
#pragma unroll
        for (int mt = 0; mt < 4; ++mt)
#pragma unroll
            for (int reg = 0; reg < 4; ++reg)
                zs[(mg * 64 + mt * 16 + quad * 4 + reg) * 136 + n] =
                    (f16)acc[mt][nt + 4][reg];
    }
    __syncthreads();
#pragma unroll
    for (int i = 0; i < 8; ++i) {
        f16x8 sv2 = *(const f16x8*)&zs[orow * 136 + oseg * 64 + i * 8];
        f16x8 av  = *(const f16x8*)&acc1[gb + i * 8];
        *(f16x8*)&acc1[gb + i * 8] = av + sv2;
    }
}

// out[bt] = o2b + sum_r o2w[r] * tanh(acc1[bt][r] + o1b[r]); one wave per bt
__global__ __launch_bounds__(256) void final_kernel(
    const f16* __restrict__ acc1, const float* __restrict__ b1,
    const float* __restrict__ w2, const float* __restrict__ b2,
    float* __restrict__ out)
{
    int lane = threadIdx.x & 63;
    int w = threadIdx.x >> 6;
    int bt = blockIdx.x * 4 + w;
    float v0 = (float)acc1[(size_t)bt * 128 + lane];
    float v1 = (float)acc1[(size_t)bt * 128 + lane + 64];
    float s = w2[lane] * fast_tanh(v0 + b1[lane]) +
              w2[lane + 64] * fast_tanh(v1 + b1[lane + 64]);
#pragma unroll
    for (int k = 1; k < 64; k <<= 1) s += __shfl_xor(s, k, 64);
    if (lane == 0) out[bt] = s + b2[0];
}

extern "C" void kernel_launch(void* const* d_in, const int* in_sizes, int n_in,
                              void* d_out, int out_size, void* d_ws, size_t ws_size,
                              hipStream_t stream)
{
    const float* x   = (const float*)d_in[0];
    const float* iw  = (const float*)d_in[1];
    const float* ib  = (const float*)d_in[2];
    const float* cw  = (const float*)d_in[3];
    const float* cb  = (const float*)d_in[4];
    const float* ow  = (const float*)d_in[5];
    const float* ob  = (const float*)d_in[6];
    const float* o1w = (const float*)d_in[7];
    const float* o1b = (const float*)d_in[8];
    const float* o2w = (const float*)d_in[9];
    const float* o2b = (const float*)d_in[10];
    float* out = (float*)d_out;

    const size_t HTR = (size_t)BATCH * T_LEN * 128;   // 16777216
    f16* hA   = (f16*)d_ws;
    f16* hB   = hA + HTR;
    f16* acc1 = hB + HTR;
    f16* wAp  = acc1 + HTR;
    f16* wBp  = wAp + (size_t)NLAYER * 12 * 256 * 32;
    // total ~ 3*32 MB + 2.4 MB = ~103 MB of ws

    prep_weights<<<4608, 256, 0, stream>>>(cw, ow, o1w, wAp, wBp);
    input_init<<<65536, 256, 0, stream>>>(x, iw, ib, hA, acc1);

    const int DIL[NLAYER] = {1, 2, 4, 8, 16, 32, 64, 128, 256};
    f16* hin = hA; f16* hout = hB;
    for (int l = 0; l < NLAYER; ++l) {
        layer_kernel<<<dim3(T_LEN / 128, BATCH), 256, 0, stream>>>(
            hin, hout, acc1,
            wAp + (size_t)l * 12 * 256 * 32, wBp + (size_t)l * 4 * 256 * 32,
            cb + l * 256, ob + l * 128, DIL[l]);
        f16* tmp = hin; hin = hout; hout = tmp;
    }
    final_kernel<<<BATCH * T_LEN / 4, 256, 0, stream>>>(acc1, o1b, o2w, o2b, out);
}

// Round 6
// 880.858 us; speedup vs baseline: 1.0376x; 1.0376x over previous
//
#include <hip/hip_runtime.h>
#include <cstdint>
#include <cstddef>

#define T_LEN 16384
#define BATCH 8
#define NLAYER 9

typedef _Float16 f16;
typedef __attribute__((ext_vector_type(8))) _Float16 f16x8;
typedef __attribute__((ext_vector_type(4))) float f32x4;
#define MFMA_F16 __builtin_amdgcn_mfma_f32_16x16x32_f16

__device__ __forceinline__ float fast_sigmoid(float x) {
    return 1.0f / (1.0f + __expf(-x));
}
__device__ __forceinline__ float fast_tanh(float x) {
    return 1.0f - 2.0f / (__expf(2.0f * x) + 1.0f);
}

// ---------------------------------------------------------------------------
// Weight prepack to fp16, B-fragment order [n][k32-chunk]:
//  wA[l][ch12][n256][kp32] = conv_w[l][n][r][tap], tap = ch>>2, r = (ch&3)*32+kp
//  wB[l][ch4][n256][kp32]: n<128 -> out_w[l][n][k]; n>=128 -> output1_w[n-128][l*128+k]
// ---------------------------------------------------------------------------
__global__ __launch_bounds__(256) void prep_weights(
    const float* __restrict__ cw, const float* __restrict__ ow,
    const float* __restrict__ o1w, f16* __restrict__ wA, f16* __restrict__ wB)
{
    int n = blockIdx.x * 256 + threadIdx.x;
    const int NA = NLAYER * 12 * 256 * 32;   // 884736
    const int NB = NLAYER * 4 * 256 * 32;    // 294912
    if (n < NA) {
        int kp = n & 31; int q = n >> 5;
        int c = q & 255; q >>= 8;
        int ch = q % 12; int l = q / 12;
        int tap = ch >> 2;
        int r = (ch & 3) * 32 + kp;
        wA[n] = (f16)cw[((size_t)(l * 256 + c) * 128 + r) * 3 + tap];
    } else if (n < NA + NB) {
        int m = n - NA;
        int kp = m & 31; int q = m >> 5;
        int c = q & 255; q >>= 8;
        int ch = q & 3; int l = q >> 2;
        int k = ch * 32 + kp;
        float v = (c < 128) ? ow[(size_t)(l * 128 + c) * 128 + k]
                            : o1w[(size_t)(c - 128) * 1152 + l * 128 + k];
        wB[m] = (f16)v;
    }
}

// h[b][t][r] = tanh(iw[r]*x[b][t] + ib[r]) (fp16);  acc1 zero-init (fp16)
__global__ __launch_bounds__(256) void input_init(
    const float* __restrict__ x, const float* __restrict__ iw,
    const float* __restrict__ ib,
    f16* __restrict__ h, f16* __restrict__ acc1)
{
    int n = blockIdx.x * 256 + threadIdx.x;
    int r = n & 127; int bt = n >> 7;
    h[n] = (f16)fast_tanh(iw[r] * x[bt] + ib[r]);
    acc1[n] = (f16)0.0f;
}

// ---------------------------------------------------------------------------
// One layer. Block 256 thr = 4 waves (mg = w&1 splits M, ng = w>>1 splits N).
// Block tile M=64 x N=256; wave tile M=32 (2 m-tiles) x N=128 (8 nt,
// gate-paired: nt<4 filter j, nt>=4 gate j+128, j = ng*64+nt*16+col).
// Phase 1: B in LDS, XOR-swizzled (chunk i of row n at i ^ ((n>>1)&3)) ->
//   ~2-way banks everywhere; double-buffered, 1 barrier/chunk. A-loads
//   hoisted to tap level (8 f16x8 burst, 4 chunks consume slices).
// Phase 2: B direct from L2; zs overlays the Bs region -> LDS 32 KB.
// launch_bounds(256,3): acc[2][8]=64 AGPR, total regs <=170 -> 12 waves/CU.
// ---------------------------------------------------------------------------
__global__ __launch_bounds__(256, 3) void layer_kernel(
    const f16* __restrict__ h_in, f16* __restrict__ h_out,
    f16* __restrict__ acc1,
    const f16* __restrict__ wA,   // [12][256][32] this layer
    const f16* __restrict__ wB,   // [4][256][32]  this layer
    const float* __restrict__ cb, // conv_b [256]
    const float* __restrict__ ob, // out_b  [128]
    int d)
{
    __shared__ __align__(16) char smem_raw[32768];
    f16* const Bsm = (f16*)smem_raw;          // phase 1: [2][8192] (32 KB)
    f16* const zs  = (f16*)smem_raw;          // phase 2: [64][136] (17.4 KB)

    const int tid  = threadIdx.x;
    const int lane = tid & 63;
    const int w4   = tid >> 6;
    const int mg   = w4 & 1;
    const int ng   = w4 >> 1;
    const int col  = lane & 15;
    const int quad = lane >> 4;
    const int b    = blockIdx.y;
    const int t0   = blockIdx.x * 64;

    const f16* hb = h_in + (size_t)b * T_LEN * 128;

    const int bswz = (quad ^ ((col >> 1) & 3)) * 8;  // swizzled chunk offset (reads)
    const int wsw  = (tid >> 1) & 3;                 // staging-write swizzle

    f32x4 acc[2][8];
#pragma unroll
    for (int mt = 0; mt < 2; ++mt)
#pragma unroll
        for (int nt = 0; nt < 8; ++nt) acc[mt][nt] = (f32x4)0.0f;

    // ---------------- Phase 1: pre = h * WA, K=384 (3 taps x 4 chunks) ------
    f16x8 sv[4];
    {
        const f16* src = wA + tid * 32;       // chunk 0
#pragma unroll
        for (int i = 0; i < 4; ++i) sv[i] = *(const f16x8*)&src[i * 8];
#pragma unroll
        for (int i = 0; i < 4; ++i)
            *(f16x8*)&Bsm[tid * 32 + ((i ^ wsw) * 8)] = sv[i];
    }
    __syncthreads();

#pragma unroll
    for (int tap = 0; tap < 3; ++tap) {
        const int off = (2 - tap) * d;
        // hoisted A-load: full 2-row x 128-ch block for this tap
        f16x8 a[2][4];
#pragma unroll
        for (int mt = 0; mt < 2; ++mt) {
            int t = t0 + mg * 32 + mt * 16 + col - off;
            if (t >= 0) {
                const f16* hp = &hb[(size_t)t * 128 + quad * 8];
#pragma unroll
                for (int c = 0; c < 4; ++c) a[mt][c] = *(const f16x8*)&hp[c * 32];
            } else {
#pragma unroll
                for (int c = 0; c < 4; ++c) a[mt][c] = (f16x8)(f16)0.0f;
            }
        }
#pragma unroll
        for (int c = 0; c < 4; ++c) {
            const int ch = tap * 4 + c;
            if (ch < 11) {
                const f16* src = wA + (ch + 1) * 8192 + tid * 32;
#pragma unroll
                for (int i = 0; i < 4; ++i) sv[i] = *(const f16x8*)&src[i * 8];
            }
            const f16* bsc = Bsm + (ch & 1) * 8192;
#pragma unroll
            for (int nt = 0; nt < 8; ++nt) {
                int nb = (nt < 4) ? (ng * 64 + nt * 16)
                                  : (128 + ng * 64 + (nt - 4) * 16);
                f16x8 bf = *(const f16x8*)&bsc[(nb + col) * 32 + bswz];
                acc[0][nt] = MFMA_F16(a[0][c], bf, acc[0][nt], 0, 0, 0);
                acc[1][nt] = MFMA_F16(a[1][c], bf, acc[1][nt], 0, 0, 0);
            }
            if (ch < 11) {
                f16* dst = Bsm + ((ch + 1) & 1) * 8192 + tid * 32;
#pragma unroll
                for (int i = 0; i < 4; ++i) *(f16x8*)&dst[(i ^ wsw) * 8] = sv[i];
            }
            __syncthreads();
        }
    }

    // ---------------- Gating -> zs[64][136] (overlays Bsm; reads drained) ---
#pragma unroll
    for (int nt = 0; nt < 4; ++nt) {
        int j = ng * 64 + nt * 16 + col;
        float cf = cb[j];
        float cg = cb[j + 128];
#pragma unroll
        for (int mt = 0; mt < 2; ++mt)
#pragma unroll
            for (int reg = 0; reg < 4; ++reg) {
                float f = acc[mt][nt][reg]     + cf;
                float g = acc[mt][nt + 4][reg] + cg;
                zs[(mg * 32 + mt * 16 + quad * 4 + reg) * 136 + j] =
                    (f16)(fast_tanh(f) * fast_sigmoid(g));
            }
    }
    __syncthreads();

    // ---------------- Phase 2: [res|skip] = z * WB, K=128; B from L2 --------
#pragma unroll
    for (int mt = 0; mt < 2; ++mt)
#pragma unroll
        for (int nt = 0; nt < 8; ++nt) acc[mt][nt] = (f32x4)0.0f;

#pragma unroll
    for (int ch = 0; ch < 4; ++ch) {
        f16x8 a[2];
#pragma unroll
        for (int mt = 0; mt < 2; ++mt)
            a[mt] = *(const f16x8*)&zs[(mg * 32 + mt * 16 + col) * 136 + ch * 32 + quad * 8];
        const f16* wc = wB + ch * 8192;
#pragma unroll
        for (int nt = 0; nt < 8; ++nt) {
            int nb = (nt < 4) ? (ng * 64 + nt * 16)
                              : (128 + ng * 64 + (nt - 4) * 16);
            f16x8 bf = *(const f16x8*)&wc[(nb + col) * 32 + quad * 8];
            acc[0][nt] = MFMA_F16(a[0], bf, acc[0][nt], 0, 0, 0);
            acc[1][nt] = MFMA_F16(a[1], bf, acc[1][nt], 0, 0, 0);
        }
    }
    __syncthreads();   // zs reads drained before epilogue overwrite

    // ---------------- Epilogue 1: h_out = h_in + res + ob (zs xpose) --------
#pragma unroll
    for (int nt = 0; nt < 4; ++nt) {
        int n = ng * 64 + nt * 16 + col;
        float o = ob[n];
#pragma unroll
        for (int mt = 0; mt < 2; ++mt)
#pragma unroll
            for (int reg = 0; reg < 4; ++reg)
                zs[(mg * 32 + mt * 16 + quad * 4 + reg) * 136 + n] =
                    (f16)(acc[mt][nt][reg] + o);
    }
    __syncthreads();
    const int orow = tid >> 2, oseg = tid & 3;
    const size_t gb = (size_t)b * T_LEN * 128 + (size_t)(t0 + orow) * 128 + oseg * 32;
#pragma unroll
    for (int i = 0; i < 4; ++i) {
        f16x8 rv = *(const f16x8*)&zs[orow * 136 + oseg * 32 + i * 8];
        f16x8 hv = *(const f16x8*)&h_in[gb + i * 8];
        *(f16x8*)&h_out[gb + i * 8] = hv + rv;
    }
    __syncthreads();

    // ---------------- Epilogue 2: acc1 += skip (zs xpose) -------------------
#pragma unroll
    for (int nt = 0; nt < 4; ++nt) {
        int n = ng * 64 + nt * 16 + col;
#pragma unroll
        for (int mt = 0; mt < 2; ++mt)
#pragma unroll
            for (int reg = 0; reg < 4; ++reg)
                zs[(mg * 32 + mt * 16 + quad * 4 + reg) * 136 + n] =
                    (f16)acc[mt][nt + 4][reg];
    }
    __syncthreads();
#pragma unroll
    for (int i = 0; i < 4; ++i) {
        f16x8 sv2 = *(const f16x8*)&zs[orow * 136 + oseg * 32 + i * 8];
        f16x8 av  = *(const f16x8*)&acc1[gb + i * 8];
        *(f16x8*)&acc1[gb + i * 8] = av + sv2;
    }
}

// out[bt] = o2b + sum_r o2w[r] * tanh(acc1[bt][r] + o1b[r]); one wave per bt
__global__ __launch_bounds__(256) void final_kernel(
    const f16* __restrict__ acc1, const float* __restrict__ b1,
    const float* __restrict__ w2, const float* __restrict__ b2,
    float* __restrict__ out)
{
    int lane = threadIdx.x & 63;
    int w = threadIdx.x >> 6;
    int bt = blockIdx.x * 4 + w;
    float v0 = (float)acc1[(size_t)bt * 128 + lane];
    float v1 = (float)acc1[(size_t)bt * 128 + lane + 64];
    float s = w2[lane] * fast_tanh(v0 + b1[lane]) +
              w2[lane + 64] * fast_tanh(v1 + b1[lane + 64]);
#pragma unroll
    for (int k = 1; k < 64; k <<= 1) s += __shfl_xor(s, k, 64);
    if (lane == 0) out[bt] = s + b2[0];
}

extern "C" void kernel_launch(void* const* d_in, const int* in_sizes, int n_in,
                              void* d_out, int out_size, void* d_ws, size_t ws_size,
                              hipStream_t stream)
{
    const float* x   = (const float*)d_in[0];
    const float* iw  = (const float*)d_in[1];
    const float* ib  = (const float*)d_in[2];
    const float* cw  = (const float*)d_in[3];
    const float* cb  = (const float*)d_in[4];
    const float* ow  = (const float*)d_in[5];
    const float* ob  = (const float*)d_in[6];
    const float* o1w = (const float*)d_in[7];
    const float* o1b = (const float*)d_in[8];
    const float* o2w = (const float*)d_in[9];
    const float* o2b = (const float*)d_in[10];
    float* out = (float*)d_out;

    const size_t HTR = (size_t)BATCH * T_LEN * 128;   // 16777216
    f16* hA   = (f16*)d_ws;
    f16* hB   = hA + HTR;
    f16* acc1 = hB + HTR;
    f16* wAp  = acc1 + HTR;
    f16* wBp  = wAp + (size_t)NLAYER * 12 * 256 * 32;
    // total ~ 3*32 MB + 2.4 MB = ~103 MB of ws

    prep_weights<<<4608, 256, 0, stream>>>(cw, ow, o1w, wAp, wBp);
    input_init<<<65536, 256, 0, stream>>>(x, iw, ib, hA, acc1);

    const int DIL[NLAYER] = {1, 2, 4, 8, 16, 32, 64, 128, 256};
    f16* hin = hA; f16* hout = hB;
    for (int l = 0; l < NLAYER; ++l) {
        layer_kernel<<<dim3(T_LEN / 64, BATCH), 256, 0, stream>>>(
            hin, hout, acc1,
            wAp + (size_t)l * 12 * 256 * 32, wBp + (size_t)l * 4 * 256 * 32,
            cb + l * 256, ob + l * 128, DIL[l]);
        f16* tmp = hin; hin = hout; hout = tmp;
    }
    final_kernel<<<BATCH * T_LEN / 4, 256, 0, stream>>>(acc1, o1b, o2w, o2b, out);
}

// Round 7
// 804.945 us; speedup vs baseline: 1.1354x; 1.0943x over previous
//
#include <hip/hip_runtime.h>
#include <cstdint>
#include <cstddef>

#define T_LEN 16384
#define BATCH 8
#define NLAYER 9

typedef _Float16 f16;
typedef __attribute__((ext_vector_type(8))) _Float16 f16x8;
typedef __attribute__((ext_vector_type(4))) float f32x4;
#define MFMA_F16 __builtin_amdgcn_mfma_f32_16x16x32_f16

__device__ __forceinline__ float fast_sigmoid(float x) {
    return 1.0f / (1.0f + __expf(-x));
}
__device__ __forceinline__ float fast_tanh(float x) {
    return 1.0f - 2.0f / (__expf(2.0f * x) + 1.0f);
}

// async global->LDS DMA, 16 B per lane (dst = wave-uniform base + lane*16)
__device__ __forceinline__ void stage16(const f16* g, f16* l) {
    __builtin_amdgcn_global_load_lds(
        (const __attribute__((address_space(1))) unsigned int*)g,
        (__attribute__((address_space(3))) unsigned int*)l, 16, 0, 0);
}

// ---------------------------------------------------------------------------
// Weight prepack to fp16, B-fragment order [n][k32-chunk].
//  wA is stored PRE-SWIZZLED: within row n, 8-element group at slot i holds
//  logical group i ^ ((n>>1)&3). The layer kernel's linear global_load_lds
//  copy then reproduces the swizzled LDS image that the bswz frag-reads use.
//  wB stays linear (phase 2 reads direct from L2).
// ---------------------------------------------------------------------------
__global__ __launch_bounds__(256) void prep_weights(
    const float* __restrict__ cw, const float* __restrict__ ow,
    const float* __restrict__ o1w, f16* __restrict__ wA, f16* __restrict__ wB)
{
    int n = blockIdx.x * 256 + threadIdx.x;
    const int NA = NLAYER * 12 * 256 * 32;   // 884736
    const int NB = NLAYER * 4 * 256 * 32;    // 294912
    if (n < NA) {
        int kp = n & 31; int q = n >> 5;
        int c = q & 255; q >>= 8;
        int ch = q % 12; int l = q / 12;
        // n is the swizzled DESTINATION slot: map back to logical k
        int i = kp >> 3, j = kp & 7;
        int il = i ^ ((c >> 1) & 3);
        int kpl = il * 8 + j;
        int tap = ch >> 2;
        int r = (ch & 3) * 32 + kpl;
        wA[n] = (f16)cw[((size_t)(l * 256 + c) * 128 + r) * 3 + tap];
    } else if (n < NA + NB) {
        int m = n - NA;
        int kp = m & 31; int q = m >> 5;
        int c = q & 255; q >>= 8;
        int ch = q & 3; int l = q >> 2;
        int k = ch * 32 + kp;
        float v = (c < 128) ? ow[(size_t)(l * 128 + c) * 128 + k]
                            : o1w[(size_t)(c - 128) * 1152 + l * 128 + k];
        wB[m] = (f16)v;
    }
}

// h[b][t][r] = tanh(iw[r]*x[b][t] + ib[r]) (fp16);  acc1 zero-init (fp16)
__global__ __launch_bounds__(256) void input_init(
    const float* __restrict__ x, const float* __restrict__ iw,
    const float* __restrict__ ib,
    f16* __restrict__ h, f16* __restrict__ acc1)
{
    int n = blockIdx.x * 256 + threadIdx.x;
    int r = n & 127; int bt = n >> 7;
    h[n] = (f16)fast_tanh(iw[r] * x[bt] + ib[r]);
    acc1[n] = (f16)0.0f;
}

// ---------------------------------------------------------------------------
// One layer. Block 256 thr = 4 waves (mg = w&1 splits M, ng = w>>1 splits N).
// Block tile M=64 x N=256; wave tile M=32 x N=128 (gate-paired filters).
// Phase 1: B staged via global_load_lds (16B/lane linear DMA of the
//   pre-swizzled global image), double-buffered, 1 barrier/chunk; A-loads
//   hoisted per tap. Phase 2: B direct from L2; zs overlays Bs -> LDS 32 KB.
// launch_bounds(256,4): acc 64 AGPR + ~60 arch VGPR -> 4 waves/SIMD.
// ---------------------------------------------------------------------------
__global__ __launch_bounds__(256, 4) void layer_kernel(
    const f16* __restrict__ h_in, f16* __restrict__ h_out,
    f16* __restrict__ acc1,
    const f16* __restrict__ wA,   // [12][256][32] this layer (pre-swizzled)
    const f16* __restrict__ wB,   // [4][256][32]  this layer (linear)
    const float* __restrict__ cb, // conv_b [256]
    const float* __restrict__ ob, // out_b  [128]
    int d)
{
    __shared__ __align__(16) char smem_raw[32768];
    f16* const Bsm = (f16*)smem_raw;          // phase 1: [2][8192] (32 KB)
    f16* const zs  = (f16*)smem_raw;          // phase 2: [64][136] (17.4 KB)

    const int tid  = threadIdx.x;
    const int lane = tid & 63;
    const int w4   = tid >> 6;
    const int mg   = w4 & 1;
    const int ng   = w4 >> 1;
    const int col  = lane & 15;
    const int quad = lane >> 4;
    const int b    = blockIdx.y;
    const int t0   = blockIdx.x * 64;

    const f16* hb = h_in + (size_t)b * T_LEN * 128;

    const int bswz = (quad ^ ((col >> 1) & 3)) * 8;  // swizzled chunk offset (reads)

    f32x4 acc[2][8];
#pragma unroll
    for (int mt = 0; mt < 2; ++mt)
#pragma unroll
        for (int nt = 0; nt < 8; ++nt) acc[mt][nt] = (f32x4)0.0f;

    // ---------------- Phase 1: pre = h * WA, K=384 (3 taps x 4 chunks) ------
    {   // DMA chunk 0 -> buf 0 (linear copy; image already swizzled)
        const f16* src = wA + w4 * 2048 + lane * 8;
        f16* dst = Bsm + w4 * 2048;
#pragma unroll
        for (int i = 0; i < 4; ++i) stage16(src + i * 512, dst + i * 512);
    }
    __syncthreads();

#pragma unroll
    for (int tap = 0; tap < 3; ++tap) {
        const int off = (2 - tap) * d;
        // hoisted A-load: full 2-row x 128-ch block for this tap
        f16x8 a[2][4];
#pragma unroll
        for (int mt = 0; mt < 2; ++mt) {
            int t = t0 + mg * 32 + mt * 16 + col - off;
            if (t >= 0) {
                const f16* hp = &hb[(size_t)t * 128 + quad * 8];
#pragma unroll
                for (int c = 0; c < 4; ++c) a[mt][c] = *(const f16x8*)&hp[c * 32];
            } else {
#pragma unroll
                for (int c = 0; c < 4; ++c) a[mt][c] = (f16x8)(f16)0.0f;
            }
        }
#pragma unroll
        for (int c = 0; c < 4; ++c) {
            const int ch = tap * 4 + c;
            if (ch < 11) {   // DMA next chunk into the other buffer
                const f16* src = wA + (ch + 1) * 8192 + w4 * 2048 + lane * 8;
                f16* dst = Bsm + ((ch + 1) & 1) * 8192 + w4 * 2048;
#pragma unroll
                for (int i = 0; i < 4; ++i) stage16(src + i * 512, dst + i * 512);
            }
            const f16* bsc = Bsm + (ch & 1) * 8192;
#pragma unroll
            for (int nt = 0; nt < 8; ++nt) {
                int nb = (nt < 4) ? (ng * 64 + nt * 16)
                                  : (128 + ng * 64 + (nt - 4) * 16);
                f16x8 bf = *(const f16x8*)&bsc[(nb + col) * 32 + bswz];
                acc[0][nt] = MFMA_F16(a[0][c], bf, acc[0][nt], 0, 0, 0);
                acc[1][nt] = MFMA_F16(a[1][c], bf, acc[1][nt], 0, 0, 0);
            }
            __syncthreads();   // drains this iter's DMA; protects buf reuse
        }
    }

    // ---------------- Gating -> zs[64][136] (overlays Bsm; reads drained) ---
#pragma unroll
    for (int nt = 0; nt < 4; ++nt) {
        int j = ng * 64 + nt * 16 + col;
        float cf = cb[j];
        float cg = cb[j + 128];
#pragma unroll
        for (int mt = 0; mt < 2; ++mt)
#pragma unroll
            for (int reg = 0; reg < 4; ++reg) {
                float f = acc[mt][nt][reg]     + cf;
                float g = acc[mt][nt + 4][reg] + cg;
                zs[(mg * 32 + mt * 16 + quad * 4 + reg) * 136 + j] =
                    (f16)(fast_tanh(f) * fast_sigmoid(g));
            }
    }
    __syncthreads();

    // ---------------- Phase 2: [res|skip] = z * WB, K=128; B from L2 --------
#pragma unroll
    for (int mt = 0; mt < 2; ++mt)
#pragma unroll
        for (int nt = 0; nt < 8; ++nt) acc[mt][nt] = (f32x4)0.0f;

#pragma unroll
    for (int ch = 0; ch < 4; ++ch) {
        f16x8 a[2];
#pragma unroll
        for (int mt = 0; mt < 2; ++mt)
            a[mt] = *(const f16x8*)&zs[(mg * 32 + mt * 16 + col) * 136 + ch * 32 + quad * 8];
        const f16* wc = wB + ch * 8192;
#pragma unroll
        for (int nt = 0; nt < 8; ++nt) {
            int nb = (nt < 4) ? (ng * 64 + nt * 16)
                              : (128 + ng * 64 + (nt - 4) * 16);
            f16x8 bf = *(const f16x8*)&wc[(nb + col) * 32 + quad * 8];
            acc[0][nt] = MFMA_F16(a[0], bf, acc[0][nt], 0, 0, 0);
            acc[1][nt] = MFMA_F16(a[1], bf, acc[1][nt], 0, 0, 0);
        }
    }
    __syncthreads();   // zs reads drained before epilogue overwrite

    // ---------------- Epilogue 1: h_out = h_in + res + ob (zs xpose) --------
#pragma unroll
    for (int nt = 0; nt < 4; ++nt) {
        int n = ng * 64 + nt * 16 + col;
        float o = ob[n];
#pragma unroll
        for (int mt = 0; mt < 2; ++mt)
#pragma unroll
            for (int reg = 0; reg < 4; ++reg)
                zs[(mg * 32 + mt * 16 + quad * 4 + reg) * 136 + n] =
                    (f16)(acc[mt][nt][reg] + o);
    }
    __syncthreads();
    const int orow = tid >> 2, oseg = tid & 3;
    const size_t gb = (size_t)b * T_LEN * 128 + (size_t)(t0 + orow) * 128 + oseg * 32;
#pragma unroll
    for (int i = 0; i < 4; ++i) {
        f16x8 rv = *(const f16x8*)&zs[orow * 136 + oseg * 32 + i * 8];
        f16x8 hv = *(const f16x8*)&h_in[gb + i * 8];
        *(f16x8*)&h_out[gb + i * 8] = hv + rv;
    }
    __syncthreads();

    // ---------------- Epilogue 2: acc1 += skip (zs xpose) -------------------
#pragma unroll
    for (int nt = 0; nt < 4; ++nt) {
        int n = ng * 64 + nt * 16 + col;
#pragma unroll
        for (int mt = 0; mt < 2; ++mt)
#pragma unroll
            for (int reg = 0; reg < 4; ++reg)
                zs[(mg * 32 + mt * 16 + quad * 4 + reg) * 136 + n] =
                    (f16)acc[mt][nt + 4][reg];
    }
    __syncthreads();
#pragma unroll
    for (int i = 0; i < 4; ++i) {
        f16x8 sv2 = *(const f16x8*)&zs[orow * 136 + oseg * 32 + i * 8];
        f16x8 av  = *(const f16x8*)&acc1[gb + i * 8];
        *(f16x8*)&acc1[gb + i * 8] = av + sv2;
    }
}

// out[bt] = o2b + sum_r o2w[r] * tanh(acc1[bt][r] + o1b[r]); one wave per bt
__global__ __launch_bounds__(256) void final_kernel(
    const f16* __restrict__ acc1, const float* __restrict__ b1,
    const float* __restrict__ w2, const float* __restrict__ b2,
    float* __restrict__ out)
{
    int lane = threadIdx.x & 63;
    int w = threadIdx.x >> 6;
    int bt = blockIdx.x * 4 + w;
    float v0 = (float)acc1[(size_t)bt * 128 + lane];
    float v1 = (float)acc1[(size_t)bt * 128 + lane + 64];
    float s = w2[lane] * fast_tanh(v0 + b1[lane]) +
              w2[lane + 64] * fast_tanh(v1 + b1[lane + 64]);
#pragma unroll
    for (int k = 1; k < 64; k <<= 1) s += __shfl_xor(s, k, 64);
    if (lane == 0) out[bt] = s + b2[0];
}

extern "C" void kernel_launch(void* const* d_in, const int* in_sizes, int n_in,
                              void* d_out, int out_size, void* d_ws, size_t ws_size,
                              hipStream_t stream)
{
    const float* x   = (const float*)d_in[0];
    const float* iw  = (const float*)d_in[1];
    const float* ib  = (const float*)d_in[2];
    const float* cw  = (const float*)d_in[3];
    const float* cb  = (const float*)d_in[4];
    const float* ow  = (const float*)d_in[5];
    const float* ob  = (const float*)d_in[6];
    const float* o1w = (const float*)d_in[7];
    const float* o1b = (const float*)d_in[8];
    const float* o2w = (const float*)d_in[9];
    const float* o2b = (const float*)d_in[10];
    float* out = (float*)d_out;

    const size_t HTR = (size_t)BATCH * T_LEN * 128;   // 16777216
    f16* hA   = (f16*)d_ws;
    f16* hB   = hA + HTR;
    f16* acc1 = hB + HTR;
    f16* wAp  = acc1 + HTR;
    f16* wBp  = wAp + (size_t)NLAYER * 12 * 256 * 32;
    // total ~ 3*32 MB + 2.4 MB = ~103 MB of ws

    prep_weights<<<4608, 256, 0, stream>>>(cw, ow, o1w, wAp, wBp);
    input_init<<<65536, 256, 0, stream>>>(x, iw, ib, hA, acc1);

    const int DIL[NLAYER] = {1, 2, 4, 8, 16, 32, 64, 128, 256};
    f16* hin = hA; f16* hout = hB;
    for (int l = 0; l < NLAYER; ++l) {
        layer_kernel<<<dim3(T_LEN / 64, BATCH), 256, 0, stream>>>(
            hin, hout, acc1,
            wAp + (size_t)l * 12 * 256 * 32, wBp + (size_t)l * 4 * 256 * 32,
            cb + l * 256, ob + l * 128, DIL[l]);
        f16* tmp = hin; hin = hout; hout = tmp;
    }
    final_kernel<<<BATCH * T_LEN / 4, 256, 0, stream>>>(acc1, o1b, o2w, o2b, out);
}